// Round 18
// baseline (131.586 us; speedup 1.0000x reference)
//
#include <hip/hip_runtime.h>
#include <hip/hip_bf16.h>

#define S_LEN 1024
#define DM 256
#define NTOK 32768
#define OWN 56          // owned output rows per block (64-row tile, 4-row halo/side)
#define NBLK 586        // ceil(32768/56)
#define W_SLICE 16384   // shorts per K-slice (2048 slots x 8)
#define W_SUB   131072  // shorts per sub-layer GEMM
#define W_LAYER 262144  // shorts per layer

typedef __attribute__((ext_vector_type(8))) short short8;
typedef __attribute__((ext_vector_type(4))) short s16x4;
typedef __attribute__((ext_vector_type(4))) float f32x4;
typedef __attribute__((ext_vector_type(2))) float f32x2;

__device__ __forceinline__ float bf2f(unsigned short u) {
    return __uint_as_float(((unsigned int)u) << 16);
}
__device__ __forceinline__ short f2bf(float f) {
    __hip_bfloat16 h = __float2bfloat16(f);   // HW RNE convert
    return *reinterpret_cast<short*>(&h);
}
// VOP3P packed-f32 ops (2 f32/lane/instr); non-volatile so scheduler may move them
__device__ __forceinline__ f32x2 pk_add(f32x2 a, f32x2 b) {
    f32x2 d; asm("v_pk_add_f32 %0, %1, %2" : "=v"(d) : "v"(a), "v"(b)); return d;
}
__device__ __forceinline__ f32x2 pk_mul(f32x2 a, f32x2 b) {
    f32x2 d; asm("v_pk_mul_f32 %0, %1, %2" : "=v"(d) : "v"(a), "v"(b)); return d;
}
__device__ __forceinline__ f32x2 pk_fma(f32x2 a, f32x2 b, f32x2 c) {
    f32x2 d; asm("v_pk_fma_f32 %0, %1, %2, %3" : "=v"(d) : "v"(a), "v"(b), "v"(c)); return d;
}
__device__ __forceinline__ f32x2 unpk_bf(unsigned int d) {
    f32x2 r;
    r[0] = __uint_as_float(d << 16);
    r[1] = __uint_as_float(d & 0xffff0000u);
    return r;
}

// ---- W convert + pre-fragmentation (layout unchanged from r13/r14) ------
__global__ void convert_w_kernel(const float* __restrict__ WF,
                                 const float* __restrict__ WB,
                                 short* __restrict__ WbF,
                                 short* __restrict__ WbB) {
    int dirv = blockIdx.y;
    const float* src = dirv ? WB : WF;
    short* dst = dirv ? WbB : WbF;
    int idx = blockIdx.x * blockDim.x + threadIdx.x;  // 65536 slots
    int chunk = idx >> 14;          // layer*2+sub
    int within = idx & 16383;
    int ks = within >> 11;
    int slot = within & 2047;
    int wvf = slot >> 6;
    int l = slot & 63;
    int wv = wvf >> 2;
    int f = wvf & 3;
    int lc = l & 15;
    int krow = l >> 4;
    int e = ((f >> 1) << 8) + wv * 32 + ((f & 1) << 4) + lc;
    int k0 = ks * 32 + krow * 8;
    const float* p = src + (size_t)chunk * W_SUB + (size_t)e * DM + k0;
    float4 a = *(const float4*)p;
    float4 b = *(const float4*)(p + 4);
    short8 v;
    v[0] = f2bf(a.x); v[1] = f2bf(a.y); v[2] = f2bf(a.z); v[3] = f2bf(a.w);
    v[4] = f2bf(b.x); v[5] = f2bf(b.y); v[6] = f2bf(b.z); v[7] = f2bf(b.w);
    *(short8*)(dst + (size_t)chunk * W_SUB + (size_t)ks * W_SLICE + (size_t)slot * 8) = v;
}

// ---- one highway sub-layer on a 64-row LDS tile -------------------------
__device__ __forceinline__ void hw_sub(short* Xs, const short* __restrict__ Wsub,
                                       const float* __restrict__ bsub,
                                       int wv, int l, int lc, int krow) {
    f32x4 zero = {0.f, 0.f, 0.f, 0.f};
    f32x4 acc[4][4];
#pragma unroll
    for (int i = 0; i < 4; i++)
#pragma unroll
        for (int j = 0; j < 4; j++) acc[i][j] = zero;

    const short* wp = Wsub + (size_t)wv * 2048 + (size_t)l * 8;
    __builtin_amdgcn_s_setprio(1);
#pragma unroll 2
    for (int ks = 0; ks < 8; ks++) {
        const short* wk = wp + (size_t)ks * W_SLICE;
        short8 w0 = *(const short8*)(wk);
        short8 w1 = *(const short8*)(wk + 512);
        short8 w2 = *(const short8*)(wk + 1024);
        short8 w3 = *(const short8*)(wk + 1536);
        int k8 = ks * 4 + krow;
#pragma unroll
        for (int mf = 0; mf < 4; mf++) {
            int row = mf * 16 + lc;
            short8 a = *(const short8*)(Xs + row * DM + ((k8 ^ (row & 7)) << 3));
            acc[mf][0] = __builtin_amdgcn_mfma_f32_16x16x32_bf16(w0, a, acc[mf][0], 0, 0, 0);
            acc[mf][1] = __builtin_amdgcn_mfma_f32_16x16x32_bf16(w1, a, acc[mf][1], 0, 0, 0);
            acc[mf][2] = __builtin_amdgcn_mfma_f32_16x16x32_bf16(w2, a, acc[mf][2], 0, 0, 0);
            acc[mf][3] = __builtin_amdgcn_mfma_f32_16x16x32_bf16(w3, a, acc[mf][3], 0, 0, 0);
        }
    }
    __builtin_amdgcn_s_setprio(0);
    __syncthreads();   // all As reads done before in-place writes

    const float* bsub2 = bsub + 256;
    const f32x2 NLOG2E = {-1.442695041f, -1.442695041f};
    const f32x2 ONE2 = {1.0f, 1.0f};
#pragma unroll
    for (int np = 0; np < 2; np++) {
        int e0 = wv * 32 + np * 16 + krow * 4;
        f32x4 bn = *(const f32x4*)(bsub + e0);
        f32x4 bg = *(const f32x4*)(bsub2 + e0);
        f32x2 bn01 = {bn[0], bn[1]}, bn23 = {bn[2], bn[3]};
        f32x2 bg01 = {bg[0], bg[1]}, bg23 = {bg[2], bg[3]};
#pragma unroll
        for (int mf = 0; mf < 4; mf++) {
            int t = mf * 16 + lc;
            int sx = t * DM + (((e0 >> 3) ^ (t & 7)) << 3) + (e0 & 7);
            uint2 xd = *(const uint2*)(Xs + sx);
            f32x2 xe01 = unpk_bf(xd.x);
            f32x2 xe23 = unpk_bf(xd.y);
            f32x4 an = acc[mf][np];
            f32x4 ag = acc[mf][np + 2];
            f32x2 nl01 = pk_add((f32x2){an[0], an[1]}, bn01);
            f32x2 nl23 = pk_add((f32x2){an[2], an[3]}, bn23);
            f32x2 gv01 = pk_add((f32x2){ag[0], ag[1]}, bg01);
            f32x2 gv23 = pk_add((f32x2){ag[2], ag[3]}, bg23);
            f32x2 t01 = pk_mul(gv01, NLOG2E);
            f32x2 t23 = pk_mul(gv23, NLOG2E);
            f32x2 ex01 = {__builtin_amdgcn_exp2f(t01[0]), __builtin_amdgcn_exp2f(t01[1])};
            f32x2 ex23 = {__builtin_amdgcn_exp2f(t23[0]), __builtin_amdgcn_exp2f(t23[1])};
            f32x2 dn01 = pk_add(ONE2, ex01);
            f32x2 dn23 = pk_add(ONE2, ex23);
            f32x2 g01 = {__builtin_amdgcn_rcpf(dn01[0]), __builtin_amdgcn_rcpf(dn01[1])};
            f32x2 g23 = {__builtin_amdgcn_rcpf(dn23[0]), __builtin_amdgcn_rcpf(dn23[1])};
            f32x2 rl01 = {fmaxf(nl01[0], 0.f), fmaxf(nl01[1], 0.f)};
            f32x2 rl23 = {fmaxf(nl23[0], 0.f), fmaxf(nl23[1], 0.f)};
            f32x2 d01 = {xe01[0] - rl01[0], xe01[1] - rl01[1]};
            f32x2 d23 = {xe23[0] - rl23[0], xe23[1] - rl23[1]};
            f32x2 y01 = pk_fma(g01, d01, rl01);
            f32x2 y23 = pk_fma(g23, d23, rl23);
            s16x4 yv;
            yv[0] = f2bf(y01[0]); yv[1] = f2bf(y01[1]);
            yv[2] = f2bf(y23[0]); yv[3] = f2bf(y23[1]);
            *(s16x4*)(Xs + sx) = yv;
        }
    }
    __syncthreads();   // y visible for next phase
}

// ---- fully fused BiLM: taps0 -> hw0a -> hw0b -> taps1(LDS) -> hw1a ->
//      hw1b -> writeout. grid (586, 2). 512 threads (8 waves).
__global__ __launch_bounds__(512, 4)
void bilm_kernel(const float* __restrict__ xin,
                 const float* __restrict__ fpad, const float* __restrict__ bpad,
                 const float* __restrict__ fw5, const float* __restrict__ bw5,
                 const short* __restrict__ WbF, const short* __restrict__ WbB,
                 const float* __restrict__ bF_, const float* __restrict__ bB_,
                 float* __restrict__ outp) {
    int dir = blockIdx.y;
    const short* Wd = dir ? WbB : WbF;
    const float* biasd = dir ? bB_ : bF_;
    const float* padd = dir ? bpad : fpad;
    const float* w5d = dir ? bw5 : fw5;
    int ch0 = dir ? 256 : 0;

    __shared__ __align__(16) short As[64 * DM];   // layer-0 tile (swizzled)
    __shared__ __align__(16) short Bs[64 * DM];   // layer-1 tile

    int tid = threadIdx.x;
    int wv = tid >> 6;
    int l = tid & 63;
    int lc = l & 15;
    int krow = l >> 4;
    int t0 = blockIdx.x * OWN;
    int base = t0 - 4;   // lrow 0 <-> token base

    // ---- phase A: layer-0 taps from global fp32 x -> As (64 rows) ----
    {
        float wj5[5];
#pragma unroll
        for (int j = 0; j < 5; j++) wj5[j] = w5d[j];
#pragma unroll
        for (int p = 0; p < 4; p++) {
            int pos = p * 512 + tid;
            int row = pos >> 5;
            int c = pos & 31;
            int d0 = c << 3;
            int tg = base + row;
            int s = tg & (S_LEN - 1);
            f32x2 a2[4];
#pragma unroll
            for (int i = 0; i < 4; i++) a2[i] = (f32x2){0.f, 0.f};
#pragma unroll
            for (int j = 0; j < 5; j++) {
                f32x2 wj2 = {wj5[j], wj5[j]};
                bool use_pad = (dir == 0) ? (s + j < 4) : (s + j >= S_LEN);
                const float* pf;
                if (use_pad) {
                    pf = (dir == 0) ? (padd + (size_t)(s + j) * DM + d0)
                                    : (padd + (size_t)(s + j - S_LEN) * DM + d0);
                } else {
                    long st = (dir == 0) ? ((long)tg + j - 4) : ((long)tg + j);
                    st = st < 0 ? 0 : (st >= NTOK ? NTOK - 1 : st);  // halo clamp
                    pf = xin + st * DM + d0;
                }
                float4 a = *(const float4*)pf;
                float4 b = *(const float4*)(pf + 4);
                a2[0] = pk_fma(wj2, (f32x2){a.x, a.y}, a2[0]);
                a2[1] = pk_fma(wj2, (f32x2){a.z, a.w}, a2[1]);
                a2[2] = pk_fma(wj2, (f32x2){b.x, b.y}, a2[2]);
                a2[3] = pk_fma(wj2, (f32x2){b.z, b.w}, a2[3]);
            }
            short8 o;
#pragma unroll
            for (int i = 0; i < 4; i++) {
                o[2 * i] = f2bf(a2[i][0]);
                o[2 * i + 1] = f2bf(a2[i][1]);
            }
            *(short8*)(As + row * DM + ((c ^ (row & 7)) << 3)) = o;
        }
    }
    __syncthreads();

    // ---- phase B: layer-0 highway (in place on As) ----
    hw_sub(As, Wd, biasd, wv, l, lc, krow);
    hw_sub(As, Wd + W_SUB, biasd + 512, wv, l, lc, krow);

    // ---- phase C: layer-1 taps from As -> Bs ----
    {
        float wj5[5];
#pragma unroll
        for (int j = 0; j < 5; j++) wj5[j] = w5d[5 + j];
        const float* padl1 = padd + 4 * DM;
#pragma unroll
        for (int p = 0; p < 4; p++) {
            int pos = p * 512 + tid;
            int row = pos >> 5;
            int c = pos & 31;
            int d0 = c << 3;
            int tg = base + row;
            int s = tg & (S_LEN - 1);
            f32x2 a2[4];
#pragma unroll
            for (int i = 0; i < 4; i++) a2[i] = (f32x2){0.f, 0.f};
#pragma unroll
            for (int j = 0; j < 5; j++) {
                f32x2 wj2 = {wj5[j], wj5[j]};
                bool use_pad = (dir == 0) ? (s + j < 4) : (s + j >= S_LEN);
                if (use_pad) {
                    const float* pf = (dir == 0) ? (padl1 + (size_t)(s + j) * DM + d0)
                                                 : (padl1 + (size_t)(s + j - S_LEN) * DM + d0);
                    float4 a = *(const float4*)pf;
                    float4 b = *(const float4*)(pf + 4);
                    a2[0] = pk_fma(wj2, (f32x2){a.x, a.y}, a2[0]);
                    a2[1] = pk_fma(wj2, (f32x2){a.z, a.w}, a2[1]);
                    a2[2] = pk_fma(wj2, (f32x2){b.x, b.y}, a2[2]);
                    a2[3] = pk_fma(wj2, (f32x2){b.z, b.w}, a2[3]);
                } else {
                    int srow = (dir == 0) ? (row + j - 4) : (row + j);
                    srow = srow < 0 ? 0 : (srow > 63 ? 63 : srow);  // halo clamp
                    uint4 dv = *(const uint4*)(As + srow * DM + ((c ^ (srow & 7)) << 3));
                    a2[0] = pk_fma(wj2, unpk_bf(dv.x), a2[0]);
                    a2[1] = pk_fma(wj2, unpk_bf(dv.y), a2[1]);
                    a2[2] = pk_fma(wj2, unpk_bf(dv.z), a2[2]);
                    a2[3] = pk_fma(wj2, unpk_bf(dv.w), a2[3]);
                }
            }
            short8 o;
#pragma unroll
            for (int i = 0; i < 4; i++) {
                o[2 * i] = f2bf(a2[i][0]);
                o[2 * i + 1] = f2bf(a2[i][1]);
            }
            *(short8*)(Bs + row * DM + ((c ^ (row & 7)) << 3)) = o;
        }
    }
    __syncthreads();

    // ---- phase D: layer-1 highway (in place on Bs) ----
    hw_sub(Bs, Wd + W_LAYER, biasd + 1024, wv, l, lc, krow);
    hw_sub(Bs, Wd + W_LAYER + W_SUB, biasd + 1536, wv, l, lc, krow);

    // ---- phase E: coalesced writeout of owned rows (lrow 4..59) ----
#pragma unroll
    for (int it = 0; it < 7; it++) {
        int pos = it * 512 + tid;        // 3584 float4 positions (56 rows x 64)
        int row = pos >> 6;
        int c4 = (pos & 63) << 2;
        int t = t0 + row;
        if (t < NTOK) {
            int lr = row + 4;
            int sx = lr * DM + (((c4 >> 3) ^ (lr & 7)) << 3) + (c4 & 7);
            s16x4 v0 = *(const s16x4*)(As + sx);
            s16x4 v1 = *(const s16x4*)(Bs + sx);
            float4 o0, o1;
            o0.x = bf2f((unsigned short)v0[0]); o0.y = bf2f((unsigned short)v0[1]);
            o0.z = bf2f((unsigned short)v0[2]); o0.w = bf2f((unsigned short)v0[3]);
            o1.x = bf2f((unsigned short)v1[0]); o1.y = bf2f((unsigned short)v1[1]);
            o1.z = bf2f((unsigned short)v1[2]); o1.w = bf2f((unsigned short)v1[3]);
            *(float4*)(outp + (size_t)t * 512 + ch0 + c4) = o0;
            *(float4*)(outp + (size_t)NTOK * 512 + (size_t)t * 512 + ch0 + c4) = o1;
        }
    }
}

extern "C" void kernel_launch(void* const* d_in, const int* in_sizes, int n_in,
                              void* d_out, int out_size, void* d_ws, size_t ws_size,
                              hipStream_t stream) {
    const float* inputs = (const float*)d_in[0];
    const float* fwd_pad = (const float*)d_in[1];
    const float* bwd_pad = (const float*)d_in[2];
    const float* fwd_w = (const float*)d_in[3];
    const float* bwd_w = (const float*)d_in[4];
    const float* fwd_hw_W = (const float*)d_in[5];
    const float* fwd_hw_b = (const float*)d_in[6];
    const float* bwd_hw_W = (const float*)d_in[7];
    const float* bwd_hw_b = (const float*)d_in[8];
    float* out = (float*)d_out;

    short* WbF = (short*)d_ws;
    short* WbB = WbF + (size_t)2 * W_LAYER;  // 2 MB total

    convert_w_kernel<<<dim3(256, 2), dim3(256), 0, stream>>>(fwd_hw_W, bwd_hw_W, WbF, WbB);

    bilm_kernel<<<dim3(NBLK, 2), dim3(512), 0, stream>>>(
        inputs, fwd_pad, bwd_pad, fwd_w, bwd_w,
        WbF, WbB, fwd_hw_b, bwd_hw_b, out);
}

// Round 19
// 127.167 us; speedup vs baseline: 1.0347x; 1.0347x over previous
//
#include <hip/hip_runtime.h>
#include <hip/hip_bf16.h>

#define S_LEN 1024
#define DM 256
#define NTOK 32768
#define OWN 60          // owned rows per block (64-row tile, one-sided 4-row halo)
#define NBLK 547        // ceil(32768/60)
#define W_SLICE 16384   // shorts per K-slice (2048 slots x 8)
#define W_SUB   131072  // shorts per sub-layer GEMM
#define W_LAYER 262144  // shorts per layer

typedef __attribute__((ext_vector_type(8))) short short8;
typedef __attribute__((ext_vector_type(4))) short s16x4;
typedef __attribute__((ext_vector_type(4))) float f32x4;

#define NLOG2E -1.442695041f

__device__ __forceinline__ float bf2f(unsigned short u) {
    return __uint_as_float(((unsigned int)u) << 16);
}
__device__ __forceinline__ short f2bf(float f) {
    __hip_bfloat16 h = __float2bfloat16(f);   // HW RNE convert
    return *reinterpret_cast<short*>(&h);
}

// ---- W convert + pre-fragmentation; gate rows pre-scaled by -log2(e) ----
// Per (layer,sub) chunk of 131072 shorts, slice ks, slot s = (wv*4+f)*64+l:
//   W[e][k0..k0+8], e = (f>>1)*256 + wv*32 + (f&1)*16 + (l&15),
//   k0 = ks*32 + (l>>4)*8.  f>=2 -> gate rows: scaled so sigmoid needs no mul.
__global__ void convert_w_kernel(const float* __restrict__ WF,
                                 const float* __restrict__ WB,
                                 short* __restrict__ WbF,
                                 short* __restrict__ WbB) {
    int dirv = blockIdx.y;
    const float* src = dirv ? WB : WF;
    short* dst = dirv ? WbB : WbF;
    int idx = blockIdx.x * blockDim.x + threadIdx.x;  // 65536 slots
    int chunk = idx >> 14;          // layer*2+sub
    int within = idx & 16383;
    int ks = within >> 11;
    int slot = within & 2047;
    int wvf = slot >> 6;
    int l = slot & 63;
    int wv = wvf >> 2;
    int f = wvf & 3;
    int lc = l & 15;
    int krow = l >> 4;
    int e = ((f >> 1) << 8) + wv * 32 + ((f & 1) << 4) + lc;
    int k0 = ks * 32 + krow * 8;
    float sc = (f >> 1) ? NLOG2E : 1.0f;
    const float* p = src + (size_t)chunk * W_SUB + (size_t)e * DM + k0;
    float4 a = *(const float4*)p;
    float4 b = *(const float4*)(p + 4);
    short8 v;
    v[0] = f2bf(sc * a.x); v[1] = f2bf(sc * a.y); v[2] = f2bf(sc * a.z); v[3] = f2bf(sc * a.w);
    v[4] = f2bf(sc * b.x); v[5] = f2bf(sc * b.y); v[6] = f2bf(sc * b.z); v[7] = f2bf(sc * b.w);
    *(short8*)(dst + (size_t)chunk * W_SUB + (size_t)ks * W_SLICE + (size_t)slot * 8) = v;
}

// ---- one highway sub-layer on a 64-row LDS tile (r17 core) --------------
__device__ __forceinline__ void hw_sub(short* Xs, const short* __restrict__ Wsub,
                                       const float* __restrict__ bsub,
                                       int wv, int l, int lc, int krow) {
    f32x4 zero = {0.f, 0.f, 0.f, 0.f};
    f32x4 acc[4][4];
#pragma unroll
    for (int i = 0; i < 4; i++)
#pragma unroll
        for (int j = 0; j < 4; j++) acc[i][j] = zero;

    const short* wp = Wsub + (size_t)wv * 2048 + (size_t)l * 8;
    __builtin_amdgcn_s_setprio(1);
#pragma unroll 2
    for (int ks = 0; ks < 8; ks++) {
        const short* wk = wp + (size_t)ks * W_SLICE;
        short8 w0 = *(const short8*)(wk);
        short8 w1 = *(const short8*)(wk + 512);
        short8 w2 = *(const short8*)(wk + 1024);
        short8 w3 = *(const short8*)(wk + 1536);
        int k8 = ks * 4 + krow;
#pragma unroll
        for (int mf = 0; mf < 4; mf++) {
            int row = mf * 16 + lc;
            short8 a = *(const short8*)(Xs + row * DM + ((k8 ^ (row & 7)) << 3));
            acc[mf][0] = __builtin_amdgcn_mfma_f32_16x16x32_bf16(w0, a, acc[mf][0], 0, 0, 0);
            acc[mf][1] = __builtin_amdgcn_mfma_f32_16x16x32_bf16(w1, a, acc[mf][1], 0, 0, 0);
            acc[mf][2] = __builtin_amdgcn_mfma_f32_16x16x32_bf16(w2, a, acc[mf][2], 0, 0, 0);
            acc[mf][3] = __builtin_amdgcn_mfma_f32_16x16x32_bf16(w3, a, acc[mf][3], 0, 0, 0);
        }
    }
    __builtin_amdgcn_s_setprio(0);
    __syncthreads();   // all As reads done before in-place writes

    const float* bsub2 = bsub + 256;
#pragma unroll
    for (int np = 0; np < 2; np++) {
        int e0 = wv * 32 + np * 16 + krow * 4;
        f32x4 bn = *(const f32x4*)(bsub + e0);
        f32x4 bgr = *(const f32x4*)(bsub2 + e0);
        f32x4 bg;                       // gate bias pre-scaled by -log2(e)
#pragma unroll
        for (int r = 0; r < 4; r++) bg[r] = NLOG2E * bgr[r];
#pragma unroll
        for (int mf = 0; mf < 4; mf++) {
            int t = mf * 16 + lc;
            int sx = t * DM + (((e0 >> 3) ^ (t & 7)) << 3) + (e0 & 7);
            s16x4 xv = *(const s16x4*)(Xs + sx);
            s16x4 yv;
#pragma unroll
            for (int r = 0; r < 4; r++) {
                float xe = bf2f((unsigned short)xv[r]);
                float nlv = acc[mf][np][r] + bn[r];
                float gv = acc[mf][np + 2][r] + bg[r];   // already -log2e scaled
                float g = __builtin_amdgcn_rcpf(1.0f + __builtin_amdgcn_exp2f(gv));
                float rl = fmaxf(nlv, 0.0f);
                float y = __builtin_fmaf(g, xe - rl, rl);  // g*x + (1-g)*relu
                yv[r] = f2bf(y);
            }
            *(s16x4*)(Xs + sx) = yv;
        }
    }
    __syncthreads();   // y visible for next phase
}

// ---- fully fused BiLM: taps0 -> hw0 -> out0 -> taps1(LDS) -> hw1 -> out1
// grid (547, 2). 512 threads (8 waves). One-sided halo:
// dir0 (fwd, causal) halo below: base = t0-4, owned lrows 4..63.
// dir1 (bwd, anticausal) halo above: base = t0, owned lrows 0..59.
__global__ __launch_bounds__(512, 4)
void bilm_kernel(const float* __restrict__ xin,
                 const float* __restrict__ fpad, const float* __restrict__ bpad,
                 const float* __restrict__ fw5, const float* __restrict__ bw5,
                 const short* __restrict__ WbF, const short* __restrict__ WbB,
                 const float* __restrict__ bF_, const float* __restrict__ bB_,
                 float* __restrict__ outp) {
    int dir = blockIdx.y;
    const short* Wd = dir ? WbB : WbF;
    const float* biasd = dir ? bB_ : bF_;
    const float* padd = dir ? bpad : fpad;
    const float* w5d = dir ? bw5 : fw5;
    int ch0 = dir ? 256 : 0;

    __shared__ __align__(16) short As[64 * DM];   // layer-0 tile (swizzled)
    __shared__ __align__(16) short Bs[64 * DM];   // layer-1 tile

    int tid = threadIdx.x;
    int wv = tid >> 6;
    int l = tid & 63;
    int lc = l & 15;
    int krow = l >> 4;
    int t0 = blockIdx.x * OWN;
    int hoff = (dir == 0) ? 4 : 0;
    int base = t0 - hoff;   // lrow 0 <-> token base

    // ---- phase A: layer-0 taps from global fp32 x -> As (64 rows) ----
    {
        float wj5[5];
#pragma unroll
        for (int j = 0; j < 5; j++) wj5[j] = w5d[j];
#pragma unroll
        for (int p = 0; p < 4; p++) {
            int pos = p * 512 + tid;
            int row = pos >> 5;
            int c = pos & 31;
            int d0 = c << 3;
            int tg = base + row;
            int s = tg & (S_LEN - 1);
            float a8[8];
#pragma unroll
            for (int i = 0; i < 8; i++) a8[i] = 0.0f;
#pragma unroll
            for (int j = 0; j < 5; j++) {
                float wj = wj5[j];
                bool use_pad = (dir == 0) ? (s + j < 4) : (s + j >= S_LEN);
                if (use_pad) {
                    const float* pf = (dir == 0) ? (padd + (size_t)(s + j) * DM + d0)
                                                 : (padd + (size_t)(s + j - S_LEN) * DM + d0);
                    const float4* q = (const float4*)pf;
                    float4 a = q[0], b = q[1];
                    a8[0] += wj * a.x; a8[1] += wj * a.y; a8[2] += wj * a.z; a8[3] += wj * a.w;
                    a8[4] += wj * b.x; a8[5] += wj * b.y; a8[6] += wj * b.z; a8[7] += wj * b.w;
                } else {
                    long st = (dir == 0) ? ((long)tg + j - 4) : ((long)tg + j);
                    st = st < 0 ? 0 : (st >= NTOK ? NTOK - 1 : st);  // halo clamp
                    const float4* q = (const float4*)(xin + st * DM + d0);
                    float4 a = q[0], b = q[1];
                    a8[0] += wj * a.x; a8[1] += wj * a.y; a8[2] += wj * a.z; a8[3] += wj * a.w;
                    a8[4] += wj * b.x; a8[5] += wj * b.y; a8[6] += wj * b.z; a8[7] += wj * b.w;
                }
            }
            short8 o;
#pragma unroll
            for (int i = 0; i < 8; i++) o[i] = f2bf(a8[i]);
            *(short8*)(As + row * DM + ((c ^ (row & 7)) << 3)) = o;
        }
    }
    __syncthreads();

    // ---- phase B: layer-0 highway (in place on As) ----
    hw_sub(As, Wd, biasd, wv, l, lc, krow);
    hw_sub(As, Wd + W_SUB, biasd + 512, wv, l, lc, krow);

    // ---- early layer-0 writeout (stores drain in background) ----
#pragma unroll
    for (int it = 0; it < 8; it++) {
        int pos = it * 512 + tid;        // 3840 float4 positions (60 rows x 64)
        if (pos < OWN * 64) {
            int row = pos >> 6;
            int c4 = (pos & 63) << 2;
            int t = t0 + row;
            if (t < NTOK) {
                int lr = row + hoff;
                int sx = lr * DM + (((c4 >> 3) ^ (lr & 7)) << 3) + (c4 & 7);
                s16x4 v0 = *(const s16x4*)(As + sx);
                float4 o0;
                o0.x = bf2f((unsigned short)v0[0]); o0.y = bf2f((unsigned short)v0[1]);
                o0.z = bf2f((unsigned short)v0[2]); o0.w = bf2f((unsigned short)v0[3]);
                *(float4*)(outp + (size_t)t * 512 + ch0 + c4) = o0;
            }
        }
    }

    // ---- phase C: layer-1 taps from As -> Bs ----
    {
        float wj5[5];
#pragma unroll
        for (int j = 0; j < 5; j++) wj5[j] = w5d[5 + j];
        const float* padl1 = padd + 4 * DM;
#pragma unroll
        for (int p = 0; p < 4; p++) {
            int pos = p * 512 + tid;
            int row = pos >> 5;
            int c = pos & 31;
            int d0 = c << 3;
            int tg = base + row;
            int s = tg & (S_LEN - 1);
            float a8[8];
#pragma unroll
            for (int i = 0; i < 8; i++) a8[i] = 0.0f;
#pragma unroll
            for (int j = 0; j < 5; j++) {
                float wj = wj5[j];
                bool use_pad = (dir == 0) ? (s + j < 4) : (s + j >= S_LEN);
                if (use_pad) {
                    const float* pf = (dir == 0) ? (padl1 + (size_t)(s + j) * DM + d0)
                                                 : (padl1 + (size_t)(s + j - S_LEN) * DM + d0);
                    const float4* q = (const float4*)pf;
                    float4 a = q[0], b = q[1];
                    a8[0] += wj * a.x; a8[1] += wj * a.y; a8[2] += wj * a.z; a8[3] += wj * a.w;
                    a8[4] += wj * b.x; a8[5] += wj * b.y; a8[6] += wj * b.z; a8[7] += wj * b.w;
                } else {
                    int srow = (dir == 0) ? (row + j - 4) : (row + j);
                    srow = srow < 0 ? 0 : (srow > 63 ? 63 : srow);  // halo clamp
                    short8 v = *(const short8*)(As + srow * DM + ((c ^ (srow & 7)) << 3));
#pragma unroll
                    for (int i = 0; i < 8; i++) a8[i] += wj * bf2f((unsigned short)v[i]);
                }
            }
            short8 o;
#pragma unroll
            for (int i = 0; i < 8; i++) o[i] = f2bf(a8[i]);
            *(short8*)(Bs + row * DM + ((c ^ (row & 7)) << 3)) = o;
        }
    }
    __syncthreads();

    // ---- phase D: layer-1 highway (in place on Bs) ----
    hw_sub(Bs, Wd + W_LAYER, biasd + 1024, wv, l, lc, krow);
    hw_sub(Bs, Wd + W_LAYER + W_SUB, biasd + 1536, wv, l, lc, krow);

    // ---- phase E: layer-1 writeout ----
#pragma unroll
    for (int it = 0; it < 8; it++) {
        int pos = it * 512 + tid;
        if (pos < OWN * 64) {
            int row = pos >> 6;
            int c4 = (pos & 63) << 2;
            int t = t0 + row;
            if (t < NTOK) {
                int lr = row + hoff;
                int sx = lr * DM + (((c4 >> 3) ^ (lr & 7)) << 3) + (c4 & 7);
                s16x4 v1 = *(const s16x4*)(Bs + sx);
                float4 o1;
                o1.x = bf2f((unsigned short)v1[0]); o1.y = bf2f((unsigned short)v1[1]);
                o1.z = bf2f((unsigned short)v1[2]); o1.w = bf2f((unsigned short)v1[3]);
                *(float4*)(outp + (size_t)NTOK * 512 + (size_t)t * 512 + ch0 + c4) = o1;
            }
        }
    }
}

extern "C" void kernel_launch(void* const* d_in, const int* in_sizes, int n_in,
                              void* d_out, int out_size, void* d_ws, size_t ws_size,
                              hipStream_t stream) {
    const float* inputs = (const float*)d_in[0];
    const float* fwd_pad = (const float*)d_in[1];
    const float* bwd_pad = (const float*)d_in[2];
    const float* fwd_w = (const float*)d_in[3];
    const float* bwd_w = (const float*)d_in[4];
    const float* fwd_hw_W = (const float*)d_in[5];
    const float* fwd_hw_b = (const float*)d_in[6];
    const float* bwd_hw_W = (const float*)d_in[7];
    const float* bwd_hw_b = (const float*)d_in[8];
    float* out = (float*)d_out;

    short* WbF = (short*)d_ws;
    short* WbB = WbF + (size_t)2 * W_LAYER;  // 2 MB total

    convert_w_kernel<<<dim3(256, 2), dim3(256), 0, stream>>>(fwd_hw_W, bwd_hw_W, WbF, WbB);

    bilm_kernel<<<dim3(NBLK, 2), dim3(512), 0, stream>>>(
        inputs, fwd_pad, bwd_pad, fwd_w, bwd_w,
        WbF, WbB, fwd_hw_b, bwd_hw_b, out);
}

// Round 22
// 120.153 us; speedup vs baseline: 1.0952x; 1.0584x over previous
//
#include <hip/hip_runtime.h>
#include <hip/hip_bf16.h>

#define S_LEN 1024
#define DM 256
#define NTOK 32768
#define OWN 60          // owned rows per block (64-row tile, one-sided 4-row halo)
#define NBLK 547        // ceil(32768/60)
#define W_SLICE 16384   // shorts per K-slice (2048 slots x 8)
#define W_SUB   131072  // shorts per sub-layer GEMM
#define W_LAYER 262144  // shorts per layer

typedef __attribute__((ext_vector_type(8))) short short8;
typedef __attribute__((ext_vector_type(4))) short s16x4;
typedef __attribute__((ext_vector_type(4))) float f32x4;

#define NLOG2E -1.442695041f

__device__ __forceinline__ float bf2f(unsigned short u) {
    return __uint_as_float(((unsigned int)u) << 16);
}
__device__ __forceinline__ short f2bf(float f) {
    __hip_bfloat16 h = __float2bfloat16(f);   // HW RNE convert
    return *reinterpret_cast<short*>(&h);
}

// ---- W convert + pre-fragmentation; gate rows pre-scaled by -log2(e) ----
// Per (layer,sub) chunk of 131072 shorts, slice ks, slot s = (wv*4+f)*64+l:
//   W[e][k0..k0+8], e = (f>>1)*256 + wv*32 + (f&1)*16 + (l&15),
//   k0 = ks*32 + (l>>4)*8.  f>=2 -> gate rows: scaled so sigmoid needs no mul.
__global__ void convert_w_kernel(const float* __restrict__ WF,
                                 const float* __restrict__ WB,
                                 short* __restrict__ WbF,
                                 short* __restrict__ WbB) {
    int dirv = blockIdx.y;
    const float* src = dirv ? WB : WF;
    short* dst = dirv ? WbB : WbF;
    int idx = blockIdx.x * blockDim.x + threadIdx.x;  // 65536 slots
    int chunk = idx >> 14;          // layer*2+sub
    int within = idx & 16383;
    int ks = within >> 11;
    int slot = within & 2047;
    int wvf = slot >> 6;
    int l = slot & 63;
    int wv = wvf >> 2;
    int f = wvf & 3;
    int lc = l & 15;
    int krow = l >> 4;
    int e = ((f >> 1) << 8) + wv * 32 + ((f & 1) << 4) + lc;
    int k0 = ks * 32 + krow * 8;
    float sc = (f >> 1) ? NLOG2E : 1.0f;
    const float* p = src + (size_t)chunk * W_SUB + (size_t)e * DM + k0;
    float4 a = *(const float4*)p;
    float4 b = *(const float4*)(p + 4);
    short8 v;
    v[0] = f2bf(sc * a.x); v[1] = f2bf(sc * a.y); v[2] = f2bf(sc * a.z); v[3] = f2bf(sc * a.w);
    v[4] = f2bf(sc * b.x); v[5] = f2bf(sc * b.y); v[6] = f2bf(sc * b.z); v[7] = f2bf(sc * b.w);
    *(short8*)(dst + (size_t)chunk * W_SUB + (size_t)ks * W_SLICE + (size_t)slot * 8) = v;
}

// ---- one highway sub-layer on a 64-row LDS tile (r17 core) --------------
__device__ __forceinline__ void hw_sub(short* Xs, const short* __restrict__ Wsub,
                                       const float* __restrict__ bsub,
                                       int wv, int l, int lc, int krow) {
    f32x4 zero = {0.f, 0.f, 0.f, 0.f};
    f32x4 acc[4][4];
#pragma unroll
    for (int i = 0; i < 4; i++)
#pragma unroll
        for (int j = 0; j < 4; j++) acc[i][j] = zero;

    const short* wp = Wsub + (size_t)wv * 2048 + (size_t)l * 8;
    __builtin_amdgcn_s_setprio(1);
#pragma unroll 2
    for (int ks = 0; ks < 8; ks++) {
        const short* wk = wp + (size_t)ks * W_SLICE;
        short8 w0 = *(const short8*)(wk);
        short8 w1 = *(const short8*)(wk + 512);
        short8 w2 = *(const short8*)(wk + 1024);
        short8 w3 = *(const short8*)(wk + 1536);
        int k8 = ks * 4 + krow;
#pragma unroll
        for (int mf = 0; mf < 4; mf++) {
            int row = mf * 16 + lc;
            short8 a = *(const short8*)(Xs + row * DM + ((k8 ^ (row & 7)) << 3));
            acc[mf][0] = __builtin_amdgcn_mfma_f32_16x16x32_bf16(w0, a, acc[mf][0], 0, 0, 0);
            acc[mf][1] = __builtin_amdgcn_mfma_f32_16x16x32_bf16(w1, a, acc[mf][1], 0, 0, 0);
            acc[mf][2] = __builtin_amdgcn_mfma_f32_16x16x32_bf16(w2, a, acc[mf][2], 0, 0, 0);
            acc[mf][3] = __builtin_amdgcn_mfma_f32_16x16x32_bf16(w3, a, acc[mf][3], 0, 0, 0);
        }
    }
    __builtin_amdgcn_s_setprio(0);
    __syncthreads();   // all As reads done before in-place writes

    const float* bsub2 = bsub + 256;
#pragma unroll
    for (int np = 0; np < 2; np++) {
        int e0 = wv * 32 + np * 16 + krow * 4;
        f32x4 bn = *(const f32x4*)(bsub + e0);
        f32x4 bgr = *(const f32x4*)(bsub2 + e0);
        f32x4 bg;                       // gate bias pre-scaled by -log2(e)
#pragma unroll
        for (int r = 0; r < 4; r++) bg[r] = NLOG2E * bgr[r];
#pragma unroll
        for (int mf = 0; mf < 4; mf++) {
            int t = mf * 16 + lc;
            int sx = t * DM + (((e0 >> 3) ^ (t & 7)) << 3) + (e0 & 7);
            s16x4 xv = *(const s16x4*)(Xs + sx);
            s16x4 yv;
#pragma unroll
            for (int r = 0; r < 4; r++) {
                float xe = bf2f((unsigned short)xv[r]);
                float nlv = acc[mf][np][r] + bn[r];
                float gv = acc[mf][np + 2][r] + bg[r];   // already -log2e scaled
                float g = __builtin_amdgcn_rcpf(1.0f + __builtin_amdgcn_exp2f(gv));
                float rl = fmaxf(nlv, 0.0f);
                float y = __builtin_fmaf(g, xe - rl, rl);  // g*x + (1-g)*relu
                yv[r] = f2bf(y);
            }
            *(s16x4*)(Xs + sx) = yv;
        }
    }
    __syncthreads();   // y visible for next phase
}

// ---- fully fused BiLM: taps0 -> hw0 -> taps1(LDS) -> hw1 -> writeout ----
// grid (547, 2). 512 threads (8 waves). One-sided halo:
// dir0 (fwd, causal) halo below: base = t0-4, owned lrows 4..63.
// dir1 (bwd, anticausal) halo above: base = t0, owned lrows 0..59.
__global__ __launch_bounds__(512, 4)
void bilm_kernel(const float* __restrict__ xin,
                 const float* __restrict__ fpad, const float* __restrict__ bpad,
                 const float* __restrict__ fw5, const float* __restrict__ bw5,
                 const short* __restrict__ WbF, const short* __restrict__ WbB,
                 const float* __restrict__ bF_, const float* __restrict__ bB_,
                 float* __restrict__ outp) {
    int dir = blockIdx.y;
    const short* Wd = dir ? WbB : WbF;
    const float* biasd = dir ? bB_ : bF_;
    const float* padd = dir ? bpad : fpad;
    const float* w5d = dir ? bw5 : fw5;
    int ch0 = dir ? 256 : 0;

    __shared__ __align__(16) short As[64 * DM];   // layer-0 tile (swizzled)
    __shared__ __align__(16) short Bs[64 * DM];   // layer-1 tile

    int tid = threadIdx.x;
    int wv = tid >> 6;
    int l = tid & 63;
    int lc = l & 15;
    int krow = l >> 4;
    int t0 = blockIdx.x * OWN;
    int hoff = (dir == 0) ? 4 : 0;
    int base = t0 - hoff;   // lrow 0 <-> token base

    // ---- phase A: layer-0 taps from global fp32 x -> As (64 rows) ----
    {
        float wj5[5];
#pragma unroll
        for (int j = 0; j < 5; j++) wj5[j] = w5d[j];
#pragma unroll
        for (int p = 0; p < 4; p++) {
            int pos = p * 512 + tid;
            int row = pos >> 5;
            int c = pos & 31;
            int d0 = c << 3;
            int tg = base + row;
            int s = tg & (S_LEN - 1);
            float a8[8];
#pragma unroll
            for (int i = 0; i < 8; i++) a8[i] = 0.0f;
#pragma unroll
            for (int j = 0; j < 5; j++) {
                float wj = wj5[j];
                bool use_pad = (dir == 0) ? (s + j < 4) : (s + j >= S_LEN);
                if (use_pad) {
                    const float* pf = (dir == 0) ? (padd + (size_t)(s + j) * DM + d0)
                                                 : (padd + (size_t)(s + j - S_LEN) * DM + d0);
                    const float4* q = (const float4*)pf;
                    float4 a = q[0], b = q[1];
                    a8[0] += wj * a.x; a8[1] += wj * a.y; a8[2] += wj * a.z; a8[3] += wj * a.w;
                    a8[4] += wj * b.x; a8[5] += wj * b.y; a8[6] += wj * b.z; a8[7] += wj * b.w;
                } else {
                    long st = (dir == 0) ? ((long)tg + j - 4) : ((long)tg + j);
                    st = st < 0 ? 0 : (st >= NTOK ? NTOK - 1 : st);  // halo clamp
                    const float4* q = (const float4*)(xin + st * DM + d0);
                    float4 a = q[0], b = q[1];
                    a8[0] += wj * a.x; a8[1] += wj * a.y; a8[2] += wj * a.z; a8[3] += wj * a.w;
                    a8[4] += wj * b.x; a8[5] += wj * b.y; a8[6] += wj * b.z; a8[7] += wj * b.w;
                }
            }
            short8 o;
#pragma unroll
            for (int i = 0; i < 8; i++) o[i] = f2bf(a8[i]);
            *(short8*)(As + row * DM + ((c ^ (row & 7)) << 3)) = o;
        }
    }
    __syncthreads();

    // ---- phase B: layer-0 highway (in place on As) ----
    hw_sub(As, Wd, biasd, wv, l, lc, krow);
    hw_sub(As, Wd + W_SUB, biasd + 512, wv, l, lc, krow);

    // ---- phase C: layer-1 taps from As -> Bs ----
    {
        float wj5[5];
#pragma unroll
        for (int j = 0; j < 5; j++) wj5[j] = w5d[5 + j];
        const float* padl1 = padd + 4 * DM;
#pragma unroll
        for (int p = 0; p < 4; p++) {
            int pos = p * 512 + tid;
            int row = pos >> 5;
            int c = pos & 31;
            int d0 = c << 3;
            int tg = base + row;
            int s = tg & (S_LEN - 1);
            float a8[8];
#pragma unroll
            for (int i = 0; i < 8; i++) a8[i] = 0.0f;
#pragma unroll
            for (int j = 0; j < 5; j++) {
                float wj = wj5[j];
                bool use_pad = (dir == 0) ? (s + j < 4) : (s + j >= S_LEN);
                if (use_pad) {
                    const float* pf = (dir == 0) ? (padl1 + (size_t)(s + j) * DM + d0)
                                                 : (padl1 + (size_t)(s + j - S_LEN) * DM + d0);
                    const float4* q = (const float4*)pf;
                    float4 a = q[0], b = q[1];
                    a8[0] += wj * a.x; a8[1] += wj * a.y; a8[2] += wj * a.z; a8[3] += wj * a.w;
                    a8[4] += wj * b.x; a8[5] += wj * b.y; a8[6] += wj * b.z; a8[7] += wj * b.w;
                } else {
                    int srow = (dir == 0) ? (row + j - 4) : (row + j);
                    srow = srow < 0 ? 0 : (srow > 63 ? 63 : srow);  // halo clamp
                    short8 v = *(const short8*)(As + srow * DM + ((c ^ (srow & 7)) << 3));
#pragma unroll
                    for (int i = 0; i < 8; i++) a8[i] += wj * bf2f((unsigned short)v[i]);
                }
            }
            short8 o;
#pragma unroll
            for (int i = 0; i < 8; i++) o[i] = f2bf(a8[i]);
            *(short8*)(Bs + row * DM + ((c ^ (row & 7)) << 3)) = o;
        }
    }
    __syncthreads();

    // ---- phase D: layer-1 highway (in place on Bs) ----
    hw_sub(Bs, Wd + W_LAYER, biasd + 1024, wv, l, lc, krow);
    hw_sub(Bs, Wd + W_LAYER + W_SUB, biasd + 1536, wv, l, lc, krow);

    // ---- phase E: coalesced writeout of owned rows (both layers) ----
#pragma unroll
    for (int it = 0; it < 8; it++) {
        int pos = it * 512 + tid;        // 3840 float4 positions (60 rows x 64)
        if (pos < OWN * 64) {
            int row = pos >> 6;
            int c4 = (pos & 63) << 2;
            int t = t0 + row;
            if (t < NTOK) {
                int lr = row + hoff;
                int sx = lr * DM + (((c4 >> 3) ^ (lr & 7)) << 3) + (c4 & 7);
                s16x4 v0 = *(const s16x4*)(As + sx);
                s16x4 v1 = *(const s16x4*)(Bs + sx);
                float4 o0, o1;
                o0.x = bf2f((unsigned short)v0[0]); o0.y = bf2f((unsigned short)v0[1]);
                o0.z = bf2f((unsigned short)v0[2]); o0.w = bf2f((unsigned short)v0[3]);
                o1.x = bf2f((unsigned short)v1[0]); o1.y = bf2f((unsigned short)v1[1]);
                o1.z = bf2f((unsigned short)v1[2]); o1.w = bf2f((unsigned short)v1[3]);
                *(float4*)(outp + (size_t)t * 512 + ch0 + c4) = o0;
                *(float4*)(outp + (size_t)NTOK * 512 + (size_t)t * 512 + ch0 + c4) = o1;
            }
        }
    }
}

extern "C" void kernel_launch(void* const* d_in, const int* in_sizes, int n_in,
                              void* d_out, int out_size, void* d_ws, size_t ws_size,
                              hipStream_t stream) {
    const float* inputs = (const float*)d_in[0];
    const float* fwd_pad = (const float*)d_in[1];
    const float* bwd_pad = (const float*)d_in[2];
    const float* fwd_w = (const float*)d_in[3];
    const float* bwd_w = (const float*)d_in[4];
    const float* fwd_hw_W = (const float*)d_in[5];
    const float* fwd_hw_b = (const float*)d_in[6];
    const float* bwd_hw_W = (const float*)d_in[7];
    const float* bwd_hw_b = (const float*)d_in[8];
    float* out = (float*)d_out;

    short* WbF = (short*)d_ws;
    short* WbB = WbF + (size_t)2 * W_LAYER;  // 2 MB total

    convert_w_kernel<<<dim3(256, 2), dim3(256), 0, stream>>>(fwd_hw_W, bwd_hw_W, WbF, WbB);

    bilm_kernel<<<dim3(NBLK, 2), dim3(512), 0, stream>>>(
        inputs, fwd_pad, bwd_pad, fwd_w, bwd_w,
        WbF, WbB, fwd_hw_b, bwd_hw_b, out);
}